// Round 6
// baseline (313.307 us; speedup 1.0000x reference)
//
#include <hip/hip_runtime.h>
#include <math.h>

#define D_DIM 768
#define NF    385
#define NSP   772          // 2*NF pad-to-4
#define BATCH 4
#define SEQ   4096
#define MROWS 16384
#define KP5   832          // stage-5 K padded to multiple of 64
#define SPECZ ((size_t)NSP * MROWS)

typedef __bf16 bf16x8 __attribute__((ext_vector_type(8)));
typedef float  f32x4  __attribute__((ext_vector_type(4)));

// async global->LDS, 16B per lane; LDS dest is wave-uniform base + lane*16
__device__ __forceinline__ void gl2lds16(const __bf16* g, __bf16* l) {
    __builtin_amdgcn_global_load_lds(
        (const __attribute__((address_space(1))) void*)g,
        (__attribute__((address_space(3))) void*)l, 16, 0, 0);
}

// ---------------------------------------------------------------------------
// Fused prologue (one dispatch, 3 independent jobs partitioned by blockIdx):
//  [0,1728): transposeW — W_z [768][768] fp32 -> WT[z][d][e] bf16
//  [1728,2240): build DFT tables FtabT [772][768] + GT [768][832]
//  [2240,3264): cvt_x — x fp32 [16384][768] -> bf16 flat
// ---------------------------------------------------------------------------
__global__ __launch_bounds__(256) void prologue(
    __bf16* __restrict__ FtabT, __bf16* __restrict__ GT,
    const float* __restrict__ W0, const float* __restrict__ W1,
    const float* __restrict__ W2, __bf16* __restrict__ WT,
    const float* __restrict__ x, __bf16* __restrict__ x16)
{
    const int bid = blockIdx.x;
    const int tid = threadIdx.x;
    if (bid < 1728) {
        // ---- transposeW ----
        __shared__ float tile[32][33];
        const int bz = bid / 576, rem = bid % 576;
        const int bx = rem % 24, by = rem / 24;
        const float* W = bz == 0 ? W0 : (bz == 1 ? W1 : W2);
        const int tx = tid & 31, ty = tid >> 5;
        const int e0 = bx * 32, d0 = by * 32;
        #pragma unroll
        for (int j = 0; j < 4; ++j)
            tile[ty + j*8][tx] = W[(size_t)(e0 + ty + j*8) * D_DIM + d0 + tx];
        __syncthreads();
        __bf16* WTz = WT + (size_t)bz * D_DIM * D_DIM;
        #pragma unroll
        for (int j = 0; j < 4; ++j)
            WTz[(size_t)(d0 + ty + j*8) * D_DIM + e0 + tx] = (__bf16)tile[tx][ty + j*8];
    } else if (bid < 2240) {
        // ---- build tables ----
        int idx = (bid - 1728) * 256 + tid;
        const int stride = 512 * 256;
        const float w0 = 6.28318530717958647692f / (float)D_DIM;
        for (int i = idx; i < NF * D_DIM; i += stride) {
            int f = i / D_DIM, e = i - f * D_DIM;
            int m = (e * f) % D_DIM;             // exact angle reduction
            float s, c;
            __sincosf(w0 * (float)m, &s, &c);
            FtabT[(size_t)(2*f)   * D_DIM + e] = (__bf16)c;
            FtabT[(size_t)(2*f+1) * D_DIM + e] = (__bf16)(-s);
            bool dcny = (f == 0) || (f == NF - 1);
            float w = dcny ? (1.0f / D_DIM) : (2.0f / D_DIM);
            GT[(size_t)e * KP5 + 2*f]     = (__bf16)(w * c);
            GT[(size_t)e * KP5 + 2*f + 1] = dcny ? (__bf16)0.0f : (__bf16)(-w * s);
        }
        for (int i = idx; i < 2 * D_DIM; i += stride)
            FtabT[(size_t)770 * D_DIM + i] = (__bf16)0.0f;
        for (int i = idx; i < D_DIM * (KP5 - 2 * NF); i += stride) {
            int r = i / (KP5 - 2 * NF), c = 2 * NF + (i % (KP5 - 2 * NF));
            GT[(size_t)r * KP5 + c] = (__bf16)0.0f;
        }
    } else {
        // ---- cvt_x ----
        int idx = (bid - 2240) * 256 + tid;
        const int stride = 1024 * 256;
        const int total8 = MROWS * D_DIM / 8;
        const float4* x4 = (const float4*)x;
        for (int i = idx; i < total8; i += stride) {
            float4 a = x4[2*i], b = x4[2*i+1];
            bf16x8 o;
            o[0]=(__bf16)a.x; o[1]=(__bf16)a.y; o[2]=(__bf16)a.z; o[3]=(__bf16)a.w;
            o[4]=(__bf16)b.x; o[5]=(__bf16)b.y; o[6]=(__bf16)b.z; o[7]=(__bf16)b.w;
            *((bf16x8*)x16 + i) = o;
        }
    }
}

// ---------------------------------------------------------------------------
// OT bf16 [772][16384] -> O bf16 [16384][832]; 64x64 tiles, 4-B packed
// accesses both sides. Rows >= 772 and O cols 772..831 read as zero.
// ---------------------------------------------------------------------------
__global__ __launch_bounds__(256) void transposeO64(
    const unsigned short* __restrict__ OT, unsigned short* __restrict__ O)
{
    __shared__ unsigned short tile[64][66];
    const int tid = threadIdx.x;
    const int m0 = blockIdx.x * 64, c0 = blockIdx.y * 64;
    const int half = tid & 31, row8 = tid >> 5;     // 32 col-pairs x 8 rows
    #pragma unroll
    for (int p = 0; p < 8; ++p) {
        const int c = c0 + p * 8 + row8;
        unsigned int v = 0;
        if (c < NSP)
            v = *(const unsigned int*)(OT + (size_t)c * MROWS + m0 + half * 2);
        *(unsigned int*)&tile[p * 8 + row8][half * 2] = v;
    }
    __syncthreads();
    #pragma unroll
    for (int p = 0; p < 8; ++p) {
        const int m = m0 + p * 8 + row8;
        const int c = c0 + half * 2;
        if (c < KP5) {
            unsigned int re = tile[half * 2][p * 8 + row8];
            unsigned int im = tile[half * 2 + 1][p * 8 + row8];
            *(unsigned int*)(O + (size_t)m * KP5 + c) = (im << 16) | re;
        }
    }
}

// ---------------------------------------------------------------------------
// bf16 NT MFMA GEMM: C[M,N] = A[M,K] @ Bt[N,K]^T
// 128x128 tile, BK=64 (halves barrier-drain count vs BK=32 — the measured
// stall), 4 waves (2x2 of 64x64), 16x16x32 MFMA, 2 K-substeps per stage.
// LDS rows are 128 B (full bank wrap); swizzle: data (row r, 16B-block c)
// lives at phys block c ^ (r&7). Fetch side: lane l loads global block
// (l&7)^((l>>3)&7); reader de-swizzles with (ks*4+lquad) ^ (lrow&7).
// grid.z batches A/B/C via strideAz/strideBz/strideCz. K % 64 == 0.
// ---------------------------------------------------------------------------
__global__ __launch_bounds__(256) void mfma_nt(
    const __bf16* __restrict__ A, const __bf16* __restrict__ B, void* __restrict__ Cv,
    int M, int N, int K, int lda, int ldb, int ldc,
    long strideAz, long strideBz, long strideCz, int c_bf16,
    const float* __restrict__ addend, const float* __restrict__ gain)
{
    __shared__ __bf16 As[128 * 64];
    __shared__ __bf16 Bs[128 * 64];
    const int tid  = threadIdx.x;
    const int wave = tid >> 6, lane = tid & 63;
    const int lrow = lane & 15, lquad = lane >> 4;
    const int wm = wave >> 1, wn = wave & 1;
    const int m0 = blockIdx.y * 128, n0 = blockIdx.x * 128;
    const __bf16* Az = A + (size_t)blockIdx.z * strideAz;
    const __bf16* Bz = B + (size_t)blockIdx.z * strideBz;

    // staging: each wave loads 32 rows (4 instrs x 8 rows) of each tile
    const int srow = lane >> 3;                         // 0..7 within instr
    const int scol = ((lane & 7) ^ srow) * 8;           // swizzled 16B block
    int ra[4], rb[4];
    #pragma unroll
    for (int i = 0; i < 4; ++i) {
        int r = m0 + wave * 32 + i * 8 + srow;
        ra[i] = r > M - 1 ? M - 1 : r;                  // stage-clamp; C guarded
        rb[i] = n0 + wave * 32 + i * 8 + srow;          // N exact multiple of 128
    }
    __bf16* ldsA = As + wave * 2048;
    __bf16* ldsB = Bs + wave * 2048;

    const int r7 = lrow & 7;                            // reader de-swizzle

    f32x4 acc[4][4];
    #pragma unroll
    for (int i = 0; i < 4; ++i)
        #pragma unroll
        for (int j = 0; j < 4; ++j)
            acc[i][j] = (f32x4){0.f, 0.f, 0.f, 0.f};

    for (int k0 = 0; k0 < K; k0 += 64) {
        #pragma unroll
        for (int i = 0; i < 4; ++i)
            gl2lds16(Az + (size_t)ra[i] * lda + k0 + scol, ldsA + i * 512);
        #pragma unroll
        for (int i = 0; i < 4; ++i)
            gl2lds16(Bz + (size_t)rb[i] * ldb + k0 + scol, ldsB + i * 512);
        __syncthreads();
        #pragma unroll
        for (int ks = 0; ks < 2; ++ks) {
            bf16x8 af[4], bfr[4];
            #pragma unroll
            for (int i = 0; i < 4; ++i) {
                const int arow = wm * 64 + i * 16 + lrow;
                const int brow = wn * 64 + i * 16 + lrow;
                const int phys = ((ks << 2) | lquad) ^ r7;
                af[i]  = *(const bf16x8*)&As[arow * 64 + phys * 8];
                bfr[i] = *(const bf16x8*)&Bs[brow * 64 + phys * 8];
            }
            #pragma unroll
            for (int i = 0; i < 4; ++i)
                #pragma unroll
                for (int j = 0; j < 4; ++j)
                    acc[i][j] = __builtin_amdgcn_mfma_f32_16x16x32_bf16(
                        af[i], bfr[j], acc[i][j], 0, 0, 0);
        }
        __syncthreads();
    }

    // C/D layout (verified m89): col = lane&15, row = (lane>>4)*4 + reg
    const int colb = n0 + wn * 64 + lrow;
    const int rowb = m0 + wm * 64 + lquad * 4;
    if (c_bf16) {
        __bf16* C = (__bf16*)Cv + (size_t)blockIdx.z * strideCz;
        #pragma unroll
        for (int i = 0; i < 4; ++i)
            #pragma unroll
            for (int j = 0; j < 4; ++j) {
                const int col = colb + j * 16;
                #pragma unroll
                for (int r = 0; r < 4; ++r) {
                    const int mm = rowb + i * 16 + r;
                    if (mm < M) C[(size_t)mm * ldc + col] = (__bf16)acc[i][j][r];
                }
            }
    } else if (addend) {
        float* C = (float*)Cv;
        const float g = gain[0];
        #pragma unroll
        for (int i = 0; i < 4; ++i)
            #pragma unroll
            for (int j = 0; j < 4; ++j) {
                const int col = colb + j * 16;
                #pragma unroll
                for (int r = 0; r < 4; ++r) {
                    const int mm = rowb + i * 16 + r;
                    if (mm < M) {
                        const size_t off = (size_t)mm * ldc + col;
                        C[off] = addend[off] + g * acc[i][j][r];
                    }
                }
            }
    } else {
        float* C = (float*)Cv + (size_t)blockIdx.z * strideCz;
        #pragma unroll
        for (int i = 0; i < 4; ++i)
            #pragma unroll
            for (int j = 0; j < 4; ++j) {
                const int col = colb + j * 16;
                #pragma unroll
                for (int r = 0; r < 4; ++r) {
                    const int mm = rowb + i * 16 + r;
                    if (mm < M) C[(size_t)mm * ldc + col] = acc[i][j][r];
                }
            }
    }
}

// ---------------------------------------------------------------------------
// Causal complex scan over bf16 spectra (transposed layout), in place over K.
// One block per (b,f) chain; thread t owns 16 consecutive s.
// ---------------------------------------------------------------------------
__global__ __launch_bounds__(256) void scan_blocks(__bf16* __restrict__ spec) {
    const int blk = blockIdx.x;
    const int b = blk / NF, f = blk % NF;
    const int tid = threadIdx.x;
    const int lane = tid & 63, wid = tid >> 6;
    const size_t colbase = (size_t)b * SEQ;
    __bf16* Kre = spec + (size_t)(2*f) * MROWS + colbase;
    __bf16* Kim = Kre + MROWS;
    const __bf16* Vre = Kre + SPECZ;
    const __bf16* Vim = Vre + MROWS;
    const __bf16* Qre = Kre + 2 * SPECZ;
    const __bf16* Qim = Qre + MROWS;
    const int s0 = tid * 16;

    bf16x8 kr0 = *(const bf16x8*)(Kre + s0), kr1 = *(const bf16x8*)(Kre + s0 + 8);
    bf16x8 ki0 = *(const bf16x8*)(Kim + s0), ki1 = *(const bf16x8*)(Kim + s0 + 8);
    bf16x8 vr0 = *(const bf16x8*)(Vre + s0), vr1 = *(const bf16x8*)(Vre + s0 + 8);
    bf16x8 vi0 = *(const bf16x8*)(Vim + s0), vi1 = *(const bf16x8*)(Vim + s0 + 8);

    float pr[16], pi[16];
    #pragma unroll
    for (int u = 0; u < 8; ++u) {
        float a = (float)kr0[u], bq = (float)ki0[u], c = (float)vr0[u], d = (float)vi0[u];
        pr[u] = a * c - bq * d;
        pi[u] = a * d + bq * c;
        float a1 = (float)kr1[u], b1 = (float)ki1[u], c1 = (float)vr1[u], d1 = (float)vi1[u];
        pr[8+u] = a1 * c1 - b1 * d1;
        pi[8+u] = a1 * d1 + b1 * c1;
    }
    #pragma unroll
    for (int j = 1; j < 16; ++j) { pr[j] += pr[j-1]; pi[j] += pi[j-1]; }
    const float totr = pr[15], toti = pi[15];

    float sr = totr, si = toti;
    #pragma unroll
    for (int d = 1; d < 64; d <<= 1) {
        float ur = __shfl_up(sr, d, 64);
        float ui = __shfl_up(si, d, 64);
        if (lane >= d) { sr += ur; si += ui; }
    }
    __shared__ float wsr[4], wsi[4];
    if (lane == 63) { wsr[wid] = sr; wsi[wid] = si; }
    __syncthreads();
    float baser = 0.f, basei = 0.f;
    #pragma unroll
    for (int w = 0; w < 3; ++w)
        if (w < wid) { baser += wsr[w]; basei += wsi[w]; }
    const float exr = baser + sr - totr;
    const float exi = basei + si - toti;

    bf16x8 qr0 = *(const bf16x8*)(Qre + s0), qr1 = *(const bf16x8*)(Qre + s0 + 8);
    bf16x8 qi0 = *(const bf16x8*)(Qim + s0), qi1 = *(const bf16x8*)(Qim + s0 + 8);
    bf16x8 outr0, outr1, outi0, outi1;
    #pragma unroll
    for (int u = 0; u < 8; ++u) {
        float mr = exr + pr[u],   mi = exi + pi[u];
        float qr = (float)qr0[u], qi = (float)qi0[u];
        outr0[u] = (__bf16)(mr * qr + mi * qi);
        outi0[u] = (__bf16)(mi * qr - mr * qi);
        float mr1 = exr + pr[8+u], mi1 = exi + pi[8+u];
        float qr_ = (float)qr1[u], qi_ = (float)qi1[u];
        outr1[u] = (__bf16)(mr1 * qr_ + mi1 * qi_);
        outi1[u] = (__bf16)(mi1 * qr_ - mr1 * qi_);
    }
    *(bf16x8*)(Kre + s0)     = outr0;
    *(bf16x8*)(Kre + s0 + 8) = outr1;
    *(bf16x8*)(Kim + s0)     = outi0;
    *(bf16x8*)(Kim + s0 + 8) = outi1;
}

// ---------------------------------------------------------------------------
// Workspace (bf16): FtabT[772*768] | GT[768*832] | WT[3*768*768]
//  | x16[16384*768] | CTs[2316*768] | spec[3*772*16384]; O overlays specV/Q.
// ---------------------------------------------------------------------------
extern "C" void kernel_launch(void* const* d_in, const int* in_sizes, int n_in,
                              void* d_out, int out_size, void* d_ws, size_t ws_size,
                              hipStream_t stream) {
    const float* x    = (const float*)d_in[0];
    const float* Wk   = (const float*)d_in[1];
    const float* Wv   = (const float*)d_in[2];
    const float* Wq   = (const float*)d_in[3];
    const float* gain = (const float*)d_in[4];
    float* out = (float*)d_out;

    __bf16* FtabT = (__bf16*)d_ws;
    __bf16* GT    = FtabT + (size_t)NSP * D_DIM;
    __bf16* WT    = GT    + (size_t)D_DIM * KP5;
    __bf16* x16   = WT    + (size_t)3 * D_DIM * D_DIM;
    __bf16* CTs   = x16   + (size_t)MROWS * D_DIM;
    __bf16* spec  = CTs   + (size_t)3 * NSP * D_DIM;
    __bf16* O     = spec  + SPECZ;   // over specV/specQ (free after scan)

    // prologue: tables + W transposes + x conversion (one dispatch)
    prologue<<<3264, 256, 0, stream>>>(FtabT, GT, Wk, Wv, Wq, WT, x, x16);

    // stage 2: CTs[z*772+c][e] = FtabT @ WT_z^T  (z-batched, stacked in M)
    mfma_nt<<<dim3(6, 7, 3), 256, 0, stream>>>(
        FtabT, WT, CTs, NSP, D_DIM, D_DIM,
        D_DIM, D_DIM, D_DIM,
        0L, (long)D_DIM * D_DIM, (long)NSP * D_DIM, 1, nullptr, nullptr);

    // stage 3: spec[2316][16384] = CTs @ x16^T  (single dispatch, M-stacked z)
    mfma_nt<<<dim3(128, 19, 1), 256, 0, stream>>>(
        CTs, x16, spec, 3 * NSP, MROWS, D_DIM,
        D_DIM, D_DIM, MROWS, 0L, 0L, 0L, 1, nullptr, nullptr);

    // stage 4: causal binding scan + unbind (in place over specK)
    scan_blocks<<<BATCH * NF, 256, 0, stream>>>(spec);

    // OT -> O bf16 [16384][832] (zero-padded cols)
    transposeO64<<<dim3(MROWS / 64, KP5 / 64), 256, 0, stream>>>(
        (const unsigned short*)spec, (unsigned short*)O);

    // stage 5: out[16384][768] = x + gain * (O @ GT^T)
    mfma_nt<<<dim3(6, 128, 1), 256, 0, stream>>>(
        O, GT, out, MROWS, D_DIM, KP5,
        KP5, KP5, D_DIM, 0L, 0L, 0L, 0, x, gain);
}